// Round 1
// baseline (891.145 us; speedup 1.0000x reference)
//
#include <hip/hip_runtime.h>
#include <hip/hip_bf16.h>

#define NPTS  20000
#define DIM   128
#define NA    1024
#define NTASK 2048
#define G     16      // tasks per dist block
#define NT    8       // N tiles
#define NPB   2500    // points per tile (NT*NPB == NPTS)
#define KSEL  50
#define GAMMA 1.0f

__global__ void zero_out_kernel(float* out) { out[0] = 0.0f; }

// Computes L1 distances for G tasks x NPB points per block.
// Task t in [0,NA): emb = out1[anchor1[t]], base = out2.
// Task t in [NA,2*NA): emb = out2[anchor2[t-NA]], base = out1.
__global__ __launch_bounds__(256) void dist_kernel(
    const float* __restrict__ out1, const float* __restrict__ out2,
    const int* __restrict__ anchor1, const int* __restrict__ anchor2,
    float* __restrict__ ws, int chunk_start)
{
    __shared__ float4 sa4[G][DIM / 4];   // 8 KB anchor embeddings
    float* sa = (float*)sa4;

    const int t0 = chunk_start + (int)blockIdx.x * G;

    // stage anchor embeddings into LDS
    for (int e = threadIdx.x; e < G * DIM; e += 256) {
        const int g = e >> 7;
        const int dd = e & (DIM - 1);
        const int t = t0 + g;
        int idx;
        const float* src;
        if (t < NA) { idx = anchor1[t];      src = out1; }
        else        { idx = anchor2[t - NA]; src = out2; }
        sa[g * DIM + dd] = src[(size_t)idx * DIM + dd];
    }
    __syncthreads();

    const float* base = (t0 < NA) ? out2 : out1;
    const int tile_start = (int)blockIdx.y * NPB;

    // 2 points per thread-iteration; point data in registers, anchors from LDS
    for (int pi = threadIdx.x; pi < NPB / 2; pi += 256) {
        const int n = tile_start + pi * 2;
        const float4* r0 = (const float4*)(base + (size_t)n * DIM);
        const float4* r1 = r0 + DIM / 4;

        float acc0[G], acc1[G];
        #pragma unroll
        for (int g = 0; g < G; ++g) { acc0[g] = 0.0f; acc1[g] = 0.0f; }

        for (int dc = 0; dc < 4; ++dc) {     // 32 dims per chunk
            float4 p0[8], p1[8];
            #pragma unroll
            for (int j = 0; j < 8; ++j) { p0[j] = r0[dc * 8 + j]; p1[j] = r1[dc * 8 + j]; }
            #pragma unroll
            for (int g = 0; g < G; ++g) {
                const float4* s4 = &sa4[g][dc * 8];
                float a0 = 0.0f, a1 = 0.0f;
                #pragma unroll
                for (int j = 0; j < 8; ++j) {
                    const float4 s = s4[j];      // broadcast LDS read (conflict-free)
                    a0 += fabsf(p0[j].x - s.x); a0 += fabsf(p0[j].y - s.y);
                    a0 += fabsf(p0[j].z - s.z); a0 += fabsf(p0[j].w - s.w);
                    a1 += fabsf(p1[j].x - s.x); a1 += fabsf(p1[j].y - s.y);
                    a1 += fabsf(p1[j].z - s.z); a1 += fabsf(p1[j].w - s.w);
                }
                acc0[g] += a0; acc1[g] += a1;
            }
        }
        #pragma unroll
        for (int g = 0; g < G; ++g) {
            float2 w; w.x = acc0[g]; w.y = acc1[g];
            *(float2*)(ws + (size_t)(t0 - chunk_start + g) * NPTS + n) = w;
        }
    }
}

// One block per task: exact 50-smallest selection via radix histogram on the
// float bit pattern (positive floats: uint bit order == float order), then
// sum relu(D - v) over the K smallest values (tie multiplicity handled).
__global__ __launch_bounds__(256) void select_kernel(
    const float* __restrict__ out1, const float* __restrict__ out2,
    const int* __restrict__ anchor1, const int* __restrict__ anchor2,
    const float* __restrict__ ws, int chunk_start, float* __restrict__ d_out)
{
    __shared__ unsigned hist[512];
    __shared__ float red[256];
    __shared__ unsigned s_prefix, s_remaining;

    const int tid = threadIdx.x;
    const int t = chunk_start + (int)blockIdx.x;
    const float* R = ws + (size_t)blockIdx.x * NPTS;

    // D = pos + GAMMA (same for both directions of anchor a)
    const int a = (t < NA) ? t : (t - NA);
    const int i1 = anchor1[a];
    const int i2 = anchor2[a];
    float p = 0.0f;
    if (tid < DIM) {
        p = fabsf(out1[(size_t)i1 * DIM + tid] - out2[(size_t)i2 * DIM + tid]);
    }
    red[tid] = p;
    __syncthreads();
    for (int s = 128; s >= 1; s >>= 1) {
        if (tid < s) red[tid] += red[tid + s];
        __syncthreads();
    }
    const float D = red[0] + GAMMA;
    __syncthreads();

    // radix select: 31 bits split 9+8+8+6 (sign always 0 for distances >= 0)
    const int shifts[4] = {22, 14, 6, 0};
    const int widths[4] = {9, 8, 8, 6};

    unsigned prefix = 0;
    unsigned remaining = KSEL;
    for (int lvl = 0; lvl < 4; ++lvl) {
        const int shift = shifts[lvl];
        const unsigned nb = 1u << widths[lvl];
        const unsigned pmask = ~((1u << (shift + widths[lvl])) - 1u);

        for (unsigned i = tid; i < nb; i += 256) hist[i] = 0;
        __syncthreads();

        for (int n = tid; n < NPTS; n += 256) {
            const unsigned key = __float_as_uint(R[n]);
            if ((key & pmask) == prefix)
                atomicAdd(&hist[(key >> shift) & (nb - 1u)], 1u);
        }
        __syncthreads();

        if (tid == 0) {
            unsigned cum = 0, b = 0;
            for (b = 0; b < nb; ++b) {
                const unsigned c = hist[b];
                if (cum + c >= remaining) break;
                cum += c;
            }
            s_prefix = prefix | (b << shift);
            s_remaining = remaining - cum;
        }
        __syncthreads();
        prefix = s_prefix;
        remaining = s_remaining;
        __syncthreads();
    }

    const unsigned kth_key = prefix;        // exact bit pattern of kth smallest
    const float kth_val = __uint_as_float(kth_key);

    float local = 0.0f;
    for (int n = tid; n < NPTS; n += 256) {
        const float v = R[n];
        if (__float_as_uint(v) < kth_key) local += fmaxf(D - v, 0.0f);
    }
    red[tid] = local;
    __syncthreads();
    for (int s = 128; s >= 1; s >>= 1) {
        if (tid < s) red[tid] += red[tid + s];
        __syncthreads();
    }
    if (tid == 0) {
        const float total = red[0] + (float)remaining * fmaxf(D - kth_val, 0.0f);
        atomicAdd(d_out, total * (1.0f / ((float)NA * (float)KSEL)));
    }
}

extern "C" void kernel_launch(void* const* d_in, const int* in_sizes, int n_in,
                              void* d_out, int out_size, void* d_ws, size_t ws_size,
                              hipStream_t stream) {
    const float* out1   = (const float*)d_in[0];
    const float* out2   = (const float*)d_in[1];
    const int*   anchor1 = (const int*)d_in[2];
    const int*   anchor2 = (const int*)d_in[3];
    float* out = (float*)d_out;
    float* ws  = (float*)d_ws;

    zero_out_kernel<<<1, 1, 0, stream>>>(out);

    // chunk tasks so the distance rows fit the workspace
    const size_t row_bytes = (size_t)NPTS * sizeof(float);
    int chunk = (int)(ws_size / row_bytes);
    chunk -= chunk % G;
    if (chunk < G) chunk = G;          // assume ws >= 1.25 MB
    if (chunk > NTASK) chunk = NTASK;

    for (int start = 0; start < NTASK; start += chunk) {
        int cur = NTASK - start;
        if (cur > chunk) cur = chunk;
        dim3 grid1(cur / G, NT);
        dist_kernel<<<grid1, 256, 0, stream>>>(out1, out2, anchor1, anchor2, ws, start);
        select_kernel<<<cur, 256, 0, stream>>>(out1, out2, anchor1, anchor2, ws, start, out);
    }
}

// Round 2
// 531.222 us; speedup vs baseline: 1.6775x; 1.6775x over previous
//
#include <hip/hip_runtime.h>
#include <hip/hip_bf16.h>

#define NPTS  20000
#define DIM   128
#define NA    1024
#define NTASK 2048
#define G     16       // tasks per dist block
#define TILE  512      // points per dist block (256 threads x 2)
#define KSEL  50
#define GAMMA 1.0f
#define FINF  0x7f800000u
#define CAP   2048

__global__ void init_kernel(float* out, unsigned* gmin) {
    const int i = (int)blockIdx.x * 256 + (int)threadIdx.x;
    if (i < NTASK) gmin[i] = FINF;
    if (i == 0) out[0] = 0.0f;
}

// L1 distances for G tasks x TILE points per block + fused per-task min.
__global__ __launch_bounds__(256) void dist_kernel(
    const float* __restrict__ out1, const float* __restrict__ out2,
    const int* __restrict__ anchor1, const int* __restrict__ anchor2,
    float* __restrict__ ws, unsigned* __restrict__ gmin, int chunk_start)
{
    __shared__ float4 sa4[G][DIM / 4];   // 8 KB anchor embeddings
    __shared__ float smin[4][G];

    const int tid = threadIdx.x;
    const int t0 = chunk_start + (int)blockIdx.x * G;

    for (int e = tid; e < G * (DIM / 4); e += 256) {
        const int g = e >> 5, c = e & 31;
        const int t = t0 + g;
        int row; const float* src;
        if (t < NA) { row = anchor1[t];      src = out1; }
        else        { row = anchor2[t - NA]; src = out2; }
        sa4[g][c] = ((const float4*)(src + (size_t)row * DIM))[c];
    }
    __syncthreads();

    const float* base = (t0 < NA) ? out2 : out1;
    const int n0 = (int)blockIdx.y * TILE + tid * 2;
    const bool valid = (n0 < NPTS);          // pairs never straddle (both even)
    const int nc = valid ? n0 : (NPTS - 2);  // clamp to stay in-bounds
    const float4* r0 = (const float4*)(base + (size_t)nc * DIM);
    const float4* r1 = r0 + DIM / 4;

    float acc0[G], acc1[G];
    #pragma unroll
    for (int g = 0; g < G; ++g) { acc0[g] = 0.0f; acc1[g] = 0.0f; }

    #pragma unroll 4
    for (int dc = 0; dc < DIM / 4; ++dc) {
        const float4 p0 = r0[dc];
        const float4 p1 = r1[dc];
        #pragma unroll
        for (int g = 0; g < G; ++g) {
            const float4 s = sa4[g][dc];   // uniform address -> LDS broadcast
            acc0[g] += fabsf(p0.x - s.x) + fabsf(p0.y - s.y)
                     + fabsf(p0.z - s.z) + fabsf(p0.w - s.w);
            acc1[g] += fabsf(p1.x - s.x) + fabsf(p1.y - s.y)
                     + fabsf(p1.z - s.z) + fabsf(p1.w - s.w);
        }
    }

    if (valid) {
        float* wrow = ws + (size_t)(t0 - chunk_start) * NPTS + n0;
        #pragma unroll
        for (int g = 0; g < G; ++g) {
            float2 w; w.x = acc0[g]; w.y = acc1[g];
            *(float2*)(wrow + (size_t)g * NPTS) = w;
        }
    }

    // fused per-task min (for select's histogram base)
    const int lane = tid & 63, wv = tid >> 6;
    #pragma unroll
    for (int g = 0; g < G; ++g) {
        float m = valid ? fminf(acc0[g], acc1[g]) : __uint_as_float(FINF);
        #pragma unroll
        for (int off = 32; off >= 1; off >>= 1)
            m = fminf(m, __shfl_xor(m, off));
        if (lane == 0) smin[wv][g] = m;
    }
    __syncthreads();
    if (tid < G) {
        const float m = fminf(fminf(smin[0][tid], smin[1][tid]),
                              fminf(smin[2][tid], smin[3][tid]));
        atomicMin(&gmin[t0 + tid], __float_as_uint(m));
    }
}

// One block per task: 2-pass selection.
// Pass A: 4096-bin histogram of (key>>14)-base (bin ~0.25 wide).
// Pass B: sum relu(D-v) for bins < kth bin; collect kth-bin candidates to LDS;
//         exact kth key via 4-level radix over the candidate list.
__global__ __launch_bounds__(256) void select_kernel(
    const float* __restrict__ out1, const float* __restrict__ out2,
    const int* __restrict__ anchor1, const int* __restrict__ anchor2,
    const float* __restrict__ ws, const unsigned* __restrict__ gmin,
    int chunk_start, float* __restrict__ d_out)
{
    __shared__ unsigned hist[4096];
    __shared__ unsigned list[CAP];
    __shared__ float red[256];
    __shared__ unsigned scan[256];
    __shared__ unsigned s_kbin, s_rem, s_cnt, s_prefix, s_rem2;

    const int tid = threadIdx.x;
    const int t = chunk_start + (int)blockIdx.x;
    const float* R = ws + (size_t)blockIdx.x * NPTS;

    // D = pos + GAMMA
    const int a = (t < NA) ? t : (t - NA);
    const int i1 = anchor1[a], i2 = anchor2[a];
    float p = 0.0f;
    if (tid < DIM) p = fabsf(out1[(size_t)i1 * DIM + tid] - out2[(size_t)i2 * DIM + tid]);
    red[tid] = p;
    __syncthreads();
    for (int s = 128; s >= 1; s >>= 1) { if (tid < s) red[tid] += red[tid + s]; __syncthreads(); }
    const float D = red[0] + GAMMA;
    __syncthreads();

    const unsigned basebin = gmin[t] >> 14;

    // ---- Pass A: histogram ----
    for (int i = tid; i < 4096; i += 256) hist[i] = 0;
    __syncthreads();
    for (int n = tid; n < NPTS; n += 256) {
        const unsigned key = __float_as_uint(R[n]);
        unsigned b = (key >> 14) - basebin; if (b > 4095u) b = 4095u;
        atomicAdd(&hist[b], 1u);
    }
    __syncthreads();

    // locate kth bin: per-thread 16-bin segment sums + parallel inclusive scan
    unsigned seg = 0;
    for (int i = 0; i < 16; ++i) seg += hist[tid * 16 + i];
    scan[tid] = seg;
    __syncthreads();
    for (int off = 1; off < 256; off <<= 1) {
        const unsigned v = scan[tid];
        const unsigned u = (tid >= off) ? scan[tid - off] : 0u;
        __syncthreads();
        scan[tid] = v + u;
        __syncthreads();
    }
    {
        const unsigned cum_before = (tid == 0) ? 0u : scan[tid - 1];
        if (cum_before < KSEL && scan[tid] >= KSEL) {
            unsigned rem = KSEL - cum_before;
            unsigned b = tid * 16;
            while (hist[b] < rem) { rem -= hist[b]; ++b; }
            s_kbin = b; s_rem = rem;
        }
        if (tid == 0) s_cnt = 0;
    }
    __syncthreads();
    const unsigned kbin = s_kbin;
    const unsigned remaining = s_rem;

    // ---- Pass B: partial sum + candidate collection ----
    float local = 0.0f;
    for (int n = tid; n < NPTS; n += 256) {
        const float v = R[n];
        const unsigned key = __float_as_uint(v);
        unsigned b = (key >> 14) - basebin; if (b > 4095u) b = 4095u;
        if (b < kbin) local += fmaxf(D - v, 0.0f);
        else if (b == kbin) {
            const unsigned i = atomicAdd(&s_cnt, 1u);
            if (i < CAP) list[i] = key;
        }
    }
    __syncthreads();
    const unsigned cnt = s_cnt;

    const int shifts[4]  = {22, 14, 6, 0};
    const int widths[4]  = {9, 8, 8, 6};

    if (cnt > CAP) {
        // exact fallback: 4-level radix over global data (rare/adversarial)
        unsigned prefix = 0, rem = KSEL;
        for (int lvl = 0; lvl < 4; ++lvl) {
            const int sh = shifts[lvl];
            const unsigned nb = 1u << widths[lvl];
            const unsigned pmask = ~((1u << (sh + widths[lvl])) - 1u);
            for (unsigned i = tid; i < nb; i += 256) hist[i] = 0;
            __syncthreads();
            for (int n = tid; n < NPTS; n += 256) {
                const unsigned key = __float_as_uint(R[n]);
                if ((key & pmask) == prefix) atomicAdd(&hist[(key >> sh) & (nb - 1u)], 1u);
            }
            __syncthreads();
            if (tid == 0) {
                unsigned cum = 0, b = 0;
                for (;; ++b) { const unsigned c = hist[b]; if (cum + c >= rem) break; cum += c; }
                s_prefix = prefix | (b << sh); s_rem2 = rem - cum;
            }
            __syncthreads();
            prefix = s_prefix; rem = s_rem2;
            __syncthreads();
        }
        const unsigned kth_key = prefix;
        const float kth_val = __uint_as_float(kth_key);
        float loc = 0.0f;
        for (int n = tid; n < NPTS; n += 256) {
            const float v = R[n];
            if (__float_as_uint(v) < kth_key) loc += fmaxf(D - v, 0.0f);
        }
        red[tid] = loc;
        __syncthreads();
        for (int s = 128; s >= 1; s >>= 1) { if (tid < s) red[tid] += red[tid + s]; __syncthreads(); }
        if (tid == 0) {
            const float total = red[0] + (float)rem * fmaxf(D - kth_val, 0.0f);
            atomicAdd(d_out, total * (1.0f / ((float)NA * (float)KSEL)));
        }
        return;
    }

    // mini radix-select over the in-LDS candidate list (exact kth key)
    unsigned prefix = 0, rem = remaining;
    for (int lvl = 0; lvl < 4; ++lvl) {
        const int sh = shifts[lvl];
        const unsigned nb = 1u << widths[lvl];
        const unsigned pmask = ~((1u << (sh + widths[lvl])) - 1u);
        for (unsigned i = tid; i < nb; i += 256) hist[i] = 0;
        __syncthreads();
        for (int i = tid; i < (int)cnt; i += 256) {
            const unsigned k = list[i];
            if ((k & pmask) == prefix) atomicAdd(&hist[(k >> sh) & (nb - 1u)], 1u);
        }
        __syncthreads();
        if (tid == 0) {
            unsigned cum = 0, b = 0;
            for (;; ++b) { const unsigned c = hist[b]; if (cum + c >= rem) break; cum += c; }
            s_prefix = prefix | (b << sh); s_rem2 = rem - cum;
        }
        __syncthreads();
        prefix = s_prefix; rem = s_rem2;
        __syncthreads();
    }
    const unsigned kth_key = prefix;
    const float kth_val = __uint_as_float(kth_key);

    float loc2 = 0.0f;
    for (int i = tid; i < (int)cnt; i += 256) {
        const unsigned k = list[i];
        if (k < kth_key) loc2 += fmaxf(D - __uint_as_float(k), 0.0f);
    }
    red[tid] = local + loc2;
    __syncthreads();
    for (int s = 128; s >= 1; s >>= 1) { if (tid < s) red[tid] += red[tid + s]; __syncthreads(); }
    if (tid == 0) {
        const float total = red[0] + (float)rem * fmaxf(D - kth_val, 0.0f);
        atomicAdd(d_out, total * (1.0f / ((float)NA * (float)KSEL)));
    }
}

extern "C" void kernel_launch(void* const* d_in, const int* in_sizes, int n_in,
                              void* d_out, int out_size, void* d_ws, size_t ws_size,
                              hipStream_t stream) {
    const float* out1    = (const float*)d_in[0];
    const float* out2    = (const float*)d_in[1];
    const int*   anchor1 = (const int*)d_in[2];
    const int*   anchor2 = (const int*)d_in[3];
    float* out = (float*)d_out;
    float* ws  = (float*)d_ws;

    // per-task min array at the tail of the workspace
    const size_t gmin_off = (ws_size - (size_t)NTASK * 4) & ~(size_t)15;
    unsigned* gmin = (unsigned*)((char*)d_ws + gmin_off);

    init_kernel<<<(NTASK + 255) / 256, 256, 0, stream>>>(out, gmin);

    const size_t row_bytes = (size_t)NPTS * sizeof(float);
    int chunk = (int)(gmin_off / row_bytes);
    chunk -= chunk % G;
    if (chunk < G) chunk = G;
    if (chunk > NTASK) chunk = NTASK;

    for (int start = 0; start < NTASK; start += chunk) {
        int cur = NTASK - start;
        if (cur > chunk) cur = chunk;
        dim3 grid1(cur / G, (NPTS + TILE - 1) / TILE);
        dist_kernel<<<grid1, 256, 0, stream>>>(out1, out2, anchor1, anchor2, ws, gmin, start);
        select_kernel<<<cur, 256, 0, stream>>>(out1, out2, anchor1, anchor2, ws, gmin, start, out);
    }
}

// Round 3
// 254.129 us; speedup vs baseline: 3.5067x; 2.0904x over previous
//
#include <hip/hip_runtime.h>
#include <hip/hip_bf16.h>

#define NPTS  20000
#define DIM   128
#define NA    1024
#define NTASK 2048
#define G     16       // tasks per dist block
#define TILE  512      // points per dist block (256 threads x 2)
#define KSEL  50
#define GAMMA 1.0f
#define NBIN  2048
#define CAP   4096

typedef unsigned short u16t;

static __device__ __forceinline__ unsigned sad16(unsigned a, unsigned b, unsigned c) {
#if __has_builtin(__builtin_amdgcn_sad_u16)
    return __builtin_amdgcn_sad_u16(a, b, c);
#else
    unsigned d;
    asm("v_sad_u16 %0, %1, %2, %3" : "=v"(d) : "v"(a), "v"(b), "v"(c));
    return d;
#endif
}

__global__ void init_kernel(float* out, unsigned* gmin, unsigned* gmax) {
    const int i = (int)blockIdx.x * 256 + (int)threadIdx.x;
    if (i < NTASK) gmin[i] = 0xFFFFFFFFu;
    if (i == 0) { out[0] = 0.0f; gmax[0] = 0u; }
}

__global__ __launch_bounds__(256) void maxabs_kernel(
    const float* __restrict__ o1, const float* __restrict__ o2,
    unsigned* __restrict__ gmax)
{
    const int nt = (int)gridDim.x * 256;
    const float4* a = (const float4*)o1;
    const float4* b = (const float4*)o2;
    float m = 0.0f;
    for (int i = (int)blockIdx.x * 256 + (int)threadIdx.x; i < NPTS * DIM / 4; i += nt) {
        const float4 x = a[i], y = b[i];
        m = fmaxf(m, fmaxf(fmaxf(fabsf(x.x), fabsf(x.y)), fmaxf(fabsf(x.z), fabsf(x.w))));
        m = fmaxf(m, fmaxf(fmaxf(fabsf(y.x), fabsf(y.y)), fmaxf(fabsf(y.z), fabsf(y.w))));
    }
    #pragma unroll
    for (int off = 32; off >= 1; off >>= 1) m = fmaxf(m, __shfl_xor(m, off));
    if ((threadIdx.x & 63) == 0) atomicMax(gmax, __float_as_uint(m));   // m >= 0: bit order == float order
}

__global__ __launch_bounds__(256) void quant_kernel(
    const float* __restrict__ o1, const float* __restrict__ o2,
    u16t* __restrict__ q1, u16t* __restrict__ q2,
    const unsigned* __restrict__ gmax)
{
    const float M = __uint_as_float(*gmax);
    const float s = 65535.0f / (2.0f * M);
    const int nt = (int)gridDim.x * 256;
    const float4* a = (const float4*)o1;
    const float4* b = (const float4*)o2;
    uint2* qa = (uint2*)q1;
    uint2* qb = (uint2*)q2;
    for (int i = (int)blockIdx.x * 256 + (int)threadIdx.x; i < NPTS * DIM / 4; i += nt) {
        const float4 x = a[i];
        unsigned u0 = __float2uint_rn((x.x + M) * s); if (u0 > 65535u) u0 = 65535u;
        unsigned u1 = __float2uint_rn((x.y + M) * s); if (u1 > 65535u) u1 = 65535u;
        unsigned u2 = __float2uint_rn((x.z + M) * s); if (u2 > 65535u) u2 = 65535u;
        unsigned u3 = __float2uint_rn((x.w + M) * s); if (u3 > 65535u) u3 = 65535u;
        uint2 oa; oa.x = u0 | (u1 << 16); oa.y = u2 | (u3 << 16);
        qa[i] = oa;
        const float4 y = b[i];
        unsigned v0 = __float2uint_rn((y.x + M) * s); if (v0 > 65535u) v0 = 65535u;
        unsigned v1 = __float2uint_rn((y.y + M) * s); if (v1 > 65535u) v1 = 65535u;
        unsigned v2 = __float2uint_rn((y.z + M) * s); if (v2 > 65535u) v2 = 65535u;
        unsigned v3 = __float2uint_rn((y.w + M) * s); if (v3 > 65535u) v3 = 65535u;
        uint2 ob; ob.x = v0 | (v1 << 16); ob.y = v2 | (v3 << 16);
        qb[i] = ob;
    }
}

// L1 distances via v_sad_u16 for G tasks x TILE points per block; writes
// (sad >> 8) as u16 per point + fused per-task min (in d16 units).
__global__ __launch_bounds__(256) void dist_kernel(
    const u16t* __restrict__ q1, const u16t* __restrict__ q2,
    const int* __restrict__ anchor1, const int* __restrict__ anchor2,
    u16t* __restrict__ wsd, unsigned* __restrict__ gmin, int chunk_start)
{
    __shared__ uint4 sa[G][16];      // 16 tasks x 128 u16 = 4 KB
    __shared__ unsigned smin[4][G];

    const int tid = threadIdx.x;
    const int t0 = chunk_start + (int)blockIdx.x * G;

    {   // stage anchor rows (u16) into LDS
        const int e = tid;           // exactly G*16 = 256 entries
        const int g = e >> 4, c = e & 15;
        const int t = t0 + g;
        int row; const u16t* src;
        if (t < NA) { row = anchor1[t];      src = q1; }
        else        { row = anchor2[t - NA]; src = q2; }
        sa[g][c] = ((const uint4*)(src + (size_t)row * DIM))[c];
    }
    __syncthreads();

    const u16t* baseq = (t0 < NA) ? q2 : q1;
    const int n0 = (int)blockIdx.y * TILE + tid * 2;
    const bool valid = (n0 < NPTS);
    const int nc = valid ? n0 : (NPTS - 2);
    const uint4* r0 = (const uint4*)(baseq + (size_t)nc * DIM);  // 16 uint4 per row
    const uint4* r1 = r0 + 16;

    unsigned acc0[G], acc1[G];
    #pragma unroll
    for (int g = 0; g < G; ++g) { acc0[g] = 0u; acc1[g] = 0u; }

    for (int c = 0; c < 8; ++c) {    // 8 chunks of 16 dims
        const uint4 pa0 = r0[2 * c], pb0 = r0[2 * c + 1];
        const uint4 pa1 = r1[2 * c], pb1 = r1[2 * c + 1];
        #pragma unroll
        for (int g = 0; g < G; ++g) {
            const uint4 s0 = sa[g][2 * c];
            const uint4 s1 = sa[g][2 * c + 1];
            unsigned a0 = acc0[g];
            a0 = sad16(pa0.x, s0.x, a0); a0 = sad16(pa0.y, s0.y, a0);
            a0 = sad16(pa0.z, s0.z, a0); a0 = sad16(pa0.w, s0.w, a0);
            a0 = sad16(pb0.x, s1.x, a0); a0 = sad16(pb0.y, s1.y, a0);
            a0 = sad16(pb0.z, s1.z, a0); a0 = sad16(pb0.w, s1.w, a0);
            acc0[g] = a0;
            unsigned a1 = acc1[g];
            a1 = sad16(pa1.x, s0.x, a1); a1 = sad16(pa1.y, s0.y, a1);
            a1 = sad16(pa1.z, s0.z, a1); a1 = sad16(pa1.w, s0.w, a1);
            a1 = sad16(pb1.x, s1.x, a1); a1 = sad16(pb1.y, s1.y, a1);
            a1 = sad16(pb1.z, s1.z, a1); a1 = sad16(pb1.w, s1.w, a1);
            acc1[g] = a1;
        }
    }

    if (valid) {
        #pragma unroll
        for (int g = 0; g < G; ++g) {
            const unsigned pack = (acc0[g] >> 8) | ((acc1[g] >> 8) << 16);
            *(unsigned*)(wsd + (size_t)(t0 - chunk_start + g) * NPTS + n0) = pack;
        }
    }

    const int lane = tid & 63, wv = tid >> 6;
    #pragma unroll
    for (int g = 0; g < G; ++g) {
        unsigned m = valid ? (min(acc0[g], acc1[g]) >> 8) : 0xFFFFFFFFu;
        #pragma unroll
        for (int off = 32; off >= 1; off >>= 1) {
            const unsigned o = (unsigned)__shfl_xor((int)m, off);
            m = m < o ? m : o;
        }
        if (lane == 0) smin[wv][g] = m;
    }
    __syncthreads();
    if (tid < G) {
        unsigned m = smin[0][tid];
        m = m < smin[1][tid] ? m : smin[1][tid];
        m = m < smin[2][tid] ? m : smin[2][tid];
        m = m < smin[3][tid] ? m : smin[3][tid];
        atomicMin(&gmin[t0 + tid], m);
    }
}

// One block per task, on u16 distance rows. Histogram (bin = d16>>4, rel. to
// per-task min), scan -> kth bin, second pass sums relu + collects kth-bin
// candidates, exact kth via 2x8-bit mini radix (full-row radix fallback).
__global__ __launch_bounds__(256) void select_kernel(
    const float* __restrict__ o1, const float* __restrict__ o2,
    const int* __restrict__ anchor1, const int* __restrict__ anchor2,
    const u16t* __restrict__ wsd, const unsigned* __restrict__ gmin,
    const unsigned* __restrict__ gmax, int chunk_start, float* __restrict__ d_out)
{
    __shared__ unsigned hist[NBIN];
    __shared__ u16t lst[CAP];
    __shared__ float red[256];
    __shared__ unsigned scn[256];
    __shared__ unsigned s_kbin, s_rem, s_cnt, s_b0, s_r1, s_k16, s_r2;

    const int tid = threadIdx.x;
    const int t = chunk_start + (int)blockIdx.x;
    const u16t* R = wsd + (size_t)blockIdx.x * NPTS;

    // D = pos + GAMMA (exact, fp32 from originals)
    const int a = (t < NA) ? t : (t - NA);
    const int i1 = anchor1[a], i2 = anchor2[a];
    float p = 0.0f;
    if (tid < DIM) p = fabsf(o1[(size_t)i1 * DIM + tid] - o2[(size_t)i2 * DIM + tid]);
    red[tid] = p;
    __syncthreads();
    for (int s = 128; s >= 1; s >>= 1) { if (tid < s) red[tid] += red[tid + s]; __syncthreads(); }
    const float D = red[0] + GAMMA;
    __syncthreads();

    const float M = __uint_as_float(*gmax);
    const float inv16 = (2.0f * M / 65535.0f) * 256.0f;   // d16 -> float distance
    const unsigned basebin = gmin[t] >> 4;

    for (int i = tid; i < NBIN; i += 256) hist[i] = 0u;
    if (tid == 0) s_cnt = 0u;
    __syncthreads();

    // ---- Pass A: histogram ----
    const uint4* R4 = (const uint4*)R;                    // 2500 uint4 (8 u16 each)
    for (int i = tid; i < NPTS / 8; i += 256) {
        const uint4 v = R4[i];
        const unsigned w[4] = {v.x, v.y, v.z, v.w};
        #pragma unroll
        for (int j = 0; j < 4; ++j) {
            unsigned bl = ((w[j] & 0xFFFFu) >> 4) - basebin; if (bl > NBIN - 1) bl = NBIN - 1;
            unsigned bh = ((w[j] >> 16) >> 4) - basebin;     if (bh > NBIN - 1) bh = NBIN - 1;
            atomicAdd(&hist[bl], 1u);
            atomicAdd(&hist[bh], 1u);
        }
    }
    __syncthreads();

    // locate kth bin: 8-bin segment sums + inclusive scan
    unsigned seg = 0;
    #pragma unroll
    for (int i = 0; i < NBIN / 256; ++i) seg += hist[tid * (NBIN / 256) + i];
    scn[tid] = seg;
    __syncthreads();
    for (int off = 1; off < 256; off <<= 1) {
        const unsigned v = scn[tid];
        const unsigned u = (tid >= off) ? scn[tid - off] : 0u;
        __syncthreads();
        scn[tid] = v + u;
        __syncthreads();
    }
    {
        const unsigned cb = (tid == 0) ? 0u : scn[tid - 1];
        if (cb < KSEL && scn[tid] >= KSEL) {
            unsigned rem = KSEL - cb;
            unsigned b = tid * (NBIN / 256);
            while (hist[b] < rem) { rem -= hist[b]; ++b; }
            s_kbin = b; s_rem = rem;
        }
    }
    __syncthreads();
    const unsigned kbin = s_kbin;
    const unsigned rem0 = s_rem;

    // ---- Pass B: partial relu-sum + candidate collection ----
    float local = 0.0f;
    for (int i = tid; i < NPTS / 8; i += 256) {
        const uint4 v = R4[i];
        const unsigned w[4] = {v.x, v.y, v.z, v.w};
        #pragma unroll
        for (int j = 0; j < 4; ++j) {
            #pragma unroll
            for (int h = 0; h < 2; ++h) {
                const unsigned u = h ? (w[j] >> 16) : (w[j] & 0xFFFFu);
                unsigned b = (u >> 4) - basebin; if (b > NBIN - 1) b = NBIN - 1;
                if (b < kbin) {
                    local += fmaxf(D - (float)u * inv16, 0.0f);
                } else if (b == kbin) {
                    const unsigned ix = atomicAdd(&s_cnt, 1u);
                    if (ix < CAP) lst[ix] = (u16t)u;
                }
            }
        }
    }
    __syncthreads();
    const unsigned cnt = s_cnt;

    unsigned kth, remf;
    if (cnt <= CAP) {
        // exact kth among kth-bin candidates: 2-level 8-bit radix in LDS
        hist[tid] = 0u;
        __syncthreads();
        for (int i = tid; i < (int)cnt; i += 256) atomicAdd(&hist[lst[i] >> 8], 1u);
        __syncthreads();
        if (tid == 0) {
            unsigned rem = rem0, b = 0;
            for (;; ++b) { const unsigned c = hist[b]; if (c >= rem) break; rem -= c; }
            s_b0 = b; s_r1 = rem;
        }
        __syncthreads();
        const unsigned b0 = s_b0;
        const unsigned r1 = s_r1;
        __syncthreads();
        hist[tid] = 0u;
        __syncthreads();
        for (int i = tid; i < (int)cnt; i += 256)
            if ((unsigned)(lst[i] >> 8) == b0) atomicAdd(&hist[lst[i] & 0xFFu], 1u);
        __syncthreads();
        if (tid == 0) {
            unsigned rem = r1, b = 0;
            for (;; ++b) { const unsigned c = hist[b]; if (c >= rem) break; rem -= c; }
            s_k16 = (b0 << 8) | b; s_r2 = rem;
        }
        __syncthreads();
        kth = s_k16; remf = s_r2;
        for (int i = tid; i < (int)cnt; i += 256) {
            const unsigned k = lst[i];
            if (k < kth) local += fmaxf(D - (float)k * inv16, 0.0f);
        }
    } else {
        // fallback: exact full-row 2-level radix (adversarial distributions)
        hist[tid] = 0u;
        __syncthreads();
        for (int i = tid; i < NPTS; i += 256) atomicAdd(&hist[R[i] >> 8], 1u);
        __syncthreads();
        if (tid == 0) {
            unsigned rem = KSEL, b = 0;
            for (;; ++b) { const unsigned c = hist[b]; if (c >= rem) break; rem -= c; }
            s_b0 = b; s_r1 = rem;
        }
        __syncthreads();
        const unsigned b0 = s_b0;
        const unsigned r1 = s_r1;
        __syncthreads();
        hist[tid] = 0u;
        __syncthreads();
        for (int i = tid; i < NPTS; i += 256)
            if ((unsigned)(R[i] >> 8) == b0) atomicAdd(&hist[R[i] & 0xFFu], 1u);
        __syncthreads();
        if (tid == 0) {
            unsigned rem = r1, b = 0;
            for (;; ++b) { const unsigned c = hist[b]; if (c >= rem) break; rem -= c; }
            s_k16 = (b0 << 8) | b; s_r2 = rem;
        }
        __syncthreads();
        kth = s_k16; remf = s_r2;
        local = 0.0f;
        for (int i = tid; i < NPTS; i += 256) {
            const unsigned u = R[i];
            if (u < kth) local += fmaxf(D - (float)u * inv16, 0.0f);
        }
    }

    red[tid] = local;
    __syncthreads();
    for (int s = 128; s >= 1; s >>= 1) { if (tid < s) red[tid] += red[tid + s]; __syncthreads(); }
    if (tid == 0) {
        const float total = red[0] + (float)remf * fmaxf(D - (float)kth * inv16, 0.0f);
        atomicAdd(d_out, total * (1.0f / ((float)NA * (float)KSEL)));
    }
}

extern "C" void kernel_launch(void* const* d_in, const int* in_sizes, int n_in,
                              void* d_out, int out_size, void* d_ws, size_t ws_size,
                              hipStream_t stream) {
    const float* o1 = (const float*)d_in[0];
    const float* o2 = (const float*)d_in[1];
    const int*   a1 = (const int*)d_in[2];
    const int*   a2 = (const int*)d_in[3];
    float* out = (float*)d_out;

    // ws layout (from the 16B-aligned end): [gmax 16B][gmin 8KB][q2 5MB][q1 5MB],
    // distance rows (u16) from the base.
    const size_t qbytes = (size_t)NPTS * DIM * 2;
    const uintptr_t end = ((uintptr_t)d_ws + ws_size) & ~(uintptr_t)15;
    unsigned* gmax = (unsigned*)(end - 16);
    unsigned* gmin = (unsigned*)(end - 16 - (size_t)NTASK * 4);
    u16t*     q2   = (u16t*)((uintptr_t)gmin - qbytes);
    u16t*     q1   = (u16t*)((uintptr_t)q2 - qbytes);
    u16t*     wsd  = (u16t*)d_ws;

    const size_t dist_region = (uintptr_t)q1 - (uintptr_t)d_ws;
    int chunk = (int)(dist_region / ((size_t)NPTS * 2));
    chunk -= chunk % G;
    if (chunk < G) chunk = G;
    if (chunk > NTASK) chunk = NTASK;

    init_kernel<<<(NTASK + 255) / 256, 256, 0, stream>>>(out, gmin, gmax);
    maxabs_kernel<<<1024, 256, 0, stream>>>(o1, o2, gmax);
    quant_kernel<<<1280, 256, 0, stream>>>(o1, o2, q1, q2, gmax);

    for (int start = 0; start < NTASK; start += chunk) {
        int cur = NTASK - start;
        if (cur > chunk) cur = chunk;
        dim3 gd(cur / G, (NPTS + TILE - 1) / TILE);
        dist_kernel<<<gd, 256, 0, stream>>>(q1, q2, a1, a2, wsd, gmin, start);
        select_kernel<<<cur, 256, 0, stream>>>(o1, o2, a1, a2, wsd, gmin, gmax, start, out);
    }
}